// Round 1
// baseline (613.113 us; speedup 1.0000x reference)
//
#include <hip/hip_runtime.h>

// GCN: 3 layers of {h = o@W; agg = Dinv A Dinv h (with self loops); BN+ReLU}, JK concat.
// N=50000, E=800000, D=128, L=3. All fp32.
//
// ws layout (~33 MB, assumed <= ws_size):
//   cnt[N] cur[N] rowptr[N+1] blksum[64] colsrc[E] colnrm[E] dinv[N] stats[256] h[N*128]

#define EPS_BN 1e-5f

__global__ void k_zero_i32(int* __restrict__ p, int n){
  int i = blockIdx.x*256 + threadIdx.x;
  if (i < n) p[i] = 0;
}
__global__ void k_zero_f32(float* __restrict__ p, int n){
  int i = blockIdx.x*256 + threadIdx.x;
  if (i < n) p[i] = 0.f;
}

__global__ void k_count(const int* __restrict__ dst, int* __restrict__ cnt, int E){
  int i = blockIdx.x*256 + threadIdx.x;
  if (i < E) atomicAdd(&cnt[dst[i]], 1);
}

__global__ void k_dinv(const int* __restrict__ cnt, float* __restrict__ dinv, int n){
  int i = blockIdx.x*256 + threadIdx.x;
  if (i < n) dinv[i] = rsqrtf((float)cnt[i] + 1.0f);  // +1 = self loop; deg>0 always
}

// exclusive scan of cnt[N] -> rowptr[N], 1024 elems/block
__global__ void k_scan1(const int* __restrict__ in, int* __restrict__ out,
                        int* __restrict__ blksum, int n){
  __shared__ int sh[256];
  int t = threadIdx.x;
  int base = blockIdx.x*1024 + t*4;
  int v[4];
  #pragma unroll
  for (int j=0;j<4;j++) v[j] = (base+j < n) ? in[base+j] : 0;
  int tsum = v[0]+v[1]+v[2]+v[3];
  sh[t] = tsum;
  __syncthreads();
  #pragma unroll
  for (int off=1; off<256; off<<=1){
    int x = (t>=off) ? sh[t-off] : 0;
    __syncthreads();
    sh[t] += x;
    __syncthreads();
  }
  if (t==255) blksum[blockIdx.x] = sh[255];
  int run = sh[t] - tsum;   // exclusive prefix of this thread's chunk
  #pragma unroll
  for (int j=0;j<4;j++){ if (base+j < n) out[base+j] = run; run += v[j]; }
}

__global__ void k_scan2(int* __restrict__ blksum, int nb){
  if (threadIdx.x == 0){
    int run = 0;
    for (int i=0;i<nb;i++){ int v = blksum[i]; blksum[i] = run; run += v; }
  }
}

__global__ void k_scan3(int* __restrict__ out, const int* __restrict__ blksum,
                        int n, int total){
  int i = blockIdx.x*256 + threadIdx.x;
  if (i < n) out[i] += blksum[i >> 10];
  if (i == 0) out[n] = total;
}

__global__ void k_fill(const int* __restrict__ src, const int* __restrict__ dst,
                       const float* __restrict__ dinv, const int* __restrict__ rowptr,
                       int* __restrict__ cur, int* __restrict__ colsrc,
                       float* __restrict__ colnrm, int E){
  int e = blockIdx.x*256 + threadIdx.x;
  if (e < E){
    int d = dst[e];
    int pos = rowptr[d] + atomicAdd(&cur[d], 1);
    int s = src[e];
    colsrc[pos] = s;
    colnrm[pos] = dinv[s];
  }
}

__global__ void k_copyx(const float4* __restrict__ x, float* __restrict__ out, int n4){
  int i = blockIdx.x*256 + threadIdx.x;
  if (i < n4){
    int v = i >> 5, f4 = i & 31;
    ((float4*)(out + (size_t)v*512))[f4] = x[i];
  }
}

// h[N,128] = A[N,128](lda=512) @ W[128,128].  W fully in LDS (64KB).
// Block: 64 rows x 128 cols, 256 threads, each thread 4 rows x 8 cols.
__launch_bounds__(256)
__global__ void k_gemm(const float* __restrict__ A, const float* __restrict__ W,
                       float* __restrict__ H, int n){
  __shared__ float4 Wl[4096];          // 64KB
  const float4* W4 = (const float4*)W;
  #pragma unroll
  for (int j=0;j<16;j++) Wl[threadIdx.x + j*256] = W4[threadIdx.x + j*256];
  __syncthreads();

  const int t  = threadIdx.x;
  const int cx = t & 15;               // col group: cols cx*8 .. +7
  const int ry = t >> 4;               // row group: rows r0 .. r0+3
  const int r0 = blockIdx.x*64 + ry*4;

  float acc[4][8];
  #pragma unroll
  for (int a=0;a<4;a++)
    #pragma unroll
    for (int b=0;b<8;b++) acc[a][b] = 0.f;

  const float4* Arow[4];
  #pragma unroll
  for (int rr=0;rr<4;rr++){
    int r = r0 + rr; if (r > n-1) r = n-1;   // clamp, skip store later
    Arow[rr] = (const float4*)(A + (size_t)r*512);
  }
  const int cb = cx*2;

  for (int k4=0;k4<32;k4++){
    float4 a0 = Arow[0][k4], a1 = Arow[1][k4], a2 = Arow[2][k4], a3 = Arow[3][k4];
    #pragma unroll
    for (int kk=0;kk<4;kk++){
      int k = k4*4 + kk;
      float4 w0 = Wl[k*32 + cb];
      float4 w1 = Wl[k*32 + cb + 1];
      float av0 = ((const float*)&a0)[kk];
      float av1 = ((const float*)&a1)[kk];
      float av2 = ((const float*)&a2)[kk];
      float av3 = ((const float*)&a3)[kk];
      float wv[8] = {w0.x,w0.y,w0.z,w0.w,w1.x,w1.y,w1.z,w1.w};
      #pragma unroll
      for (int c=0;c<8;c++){
        acc[0][c] = fmaf(av0, wv[c], acc[0][c]);
        acc[1][c] = fmaf(av1, wv[c], acc[1][c]);
        acc[2][c] = fmaf(av2, wv[c], acc[2][c]);
        acc[3][c] = fmaf(av3, wv[c], acc[3][c]);
      }
    }
  }
  #pragma unroll
  for (int rr=0;rr<4;rr++){
    int r = r0 + rr;
    if (r < n){
      float4* Hp = (float4*)(H + (size_t)r*128 + cx*8);
      Hp[0] = make_float4(acc[rr][0],acc[rr][1],acc[rr][2],acc[rr][3]);
      Hp[1] = make_float4(acc[rr][4],acc[rr][5],acc[rr][6],acc[rr][7]);
    }
  }
}

// Pull-based aggregation + fused BN-stats partial sums.
// block = 128 threads (f = feature), 32 nodes per block serially.
__launch_bounds__(128)
__global__ void k_agg(const float* __restrict__ h, const int* __restrict__ rowptr,
                      const int* __restrict__ colsrc, const float* __restrict__ colnrm,
                      const float* __restrict__ dinv, float* __restrict__ out,
                      int colOff, float* __restrict__ stats, int n){
  const int f = threadIdx.x;
  const int v0 = blockIdx.x*32;
  float s = 0.f, s2 = 0.f;
  for (int vi=0; vi<32; vi++){
    int v = v0 + vi;
    if (v >= n) break;                        // uniform across block
    int beg = rowptr[v], end = rowptr[v+1];
    float acc = 0.f;
    int j = beg;
    for (; j+3 < end; j += 4){                // unroll 4: overlap gather latency
      int   u0 = colsrc[j],   u1 = colsrc[j+1], u2 = colsrc[j+2], u3 = colsrc[j+3];
      float w0 = colnrm[j],   w1 = colnrm[j+1], w2 = colnrm[j+2], w3 = colnrm[j+3];
      float h0 = h[(size_t)u0*128 + f];
      float h1 = h[(size_t)u1*128 + f];
      float h2 = h[(size_t)u2*128 + f];
      float h3 = h[(size_t)u3*128 + f];
      acc = fmaf(w0,h0,acc); acc = fmaf(w1,h1,acc);
      acc = fmaf(w2,h2,acc); acc = fmaf(w3,h3,acc);
    }
    for (; j < end; j++){
      int u = colsrc[j];
      acc = fmaf(colnrm[j], h[(size_t)u*128 + f], acc);
    }
    float dv = dinv[v];
    acc = dv * (acc + dv * h[(size_t)v*128 + f]);   // self loop
    out[(size_t)v*512 + colOff + f] = acc;
    s += acc; s2 = fmaf(acc, acc, s2);
  }
  atomicAdd(&stats[f],       s);
  atomicAdd(&stats[128 + f], s2);
}

__global__ void k_bnrelu(float* __restrict__ out, int colOff,
                         const float* __restrict__ stats,
                         const float* __restrict__ gamma, const float* __restrict__ beta,
                         int n){
  int i = blockIdx.x*256 + threadIdx.x;
  if (i >= n*128) return;
  int v = i >> 7, f = i & 127;
  float invn = 1.0f / (float)n;
  float mu  = stats[f] * invn;
  float var = stats[128 + f] * invn - mu*mu;
  float rs  = rsqrtf(var + EPS_BN);
  size_t idx = (size_t)v*512 + colOff + f;
  float val = out[idx];
  val = gamma[f] * (val - mu) * rs + beta[f];
  out[idx] = fmaxf(val, 0.f);
}

extern "C" void kernel_launch(void* const* d_in, const int* in_sizes, int n_in,
                              void* d_out, int out_size, void* d_ws, size_t ws_size,
                              hipStream_t stream){
  const float* x      = (const float*)d_in[0];
  const int*   ei     = (const int*)d_in[1];
  const float* Ws     = (const float*)d_in[2];
  // d_in[3] = bs: cancels exactly in BatchNorm (agg+b - mean(agg+b) = agg - mean(agg))
  const float* gammas = (const float*)d_in[4];
  const float* betas  = (const float*)d_in[5];
  const int N = in_sizes[0] / 128;
  const int E = in_sizes[1] / 2;
  float* out = (float*)d_out;

  char* w = (char*)d_ws;
  auto alloc = [&](size_t bytes)->char*{
    char* p = w; w += (bytes + 255) & ~(size_t)255; return p;
  };
  int*   cnt    = (int*)  alloc((size_t)N*4);
  int*   cur    = (int*)  alloc((size_t)N*4);
  int*   rowptr = (int*)  alloc((size_t)(N+1)*4);
  int*   blksum = (int*)  alloc(64*4);
  int*   colsrc = (int*)  alloc((size_t)E*4);
  float* colnrm = (float*)alloc((size_t)E*4);
  float* dinv   = (float*)alloc((size_t)N*4);
  float* stats  = (float*)alloc(256*4);
  float* h      = (float*)alloc((size_t)N*128*4);

  const int* srcArr = ei;
  const int* dstArr = ei + E;

  const int nbN = (N + 255)/256;
  const int nbE = (E + 255)/256;
  const int nscan = (N + 1023)/1024;

  k_zero_i32<<<nbN,256,0,stream>>>(cnt, N);
  k_zero_i32<<<nbN,256,0,stream>>>(cur, N);
  k_count<<<nbE,256,0,stream>>>(dstArr, cnt, E);
  k_dinv<<<nbN,256,0,stream>>>(cnt, dinv, N);
  k_scan1<<<nscan,256,0,stream>>>(cnt, rowptr, blksum, N);
  k_scan2<<<1,64,0,stream>>>(blksum, nscan);
  k_scan3<<<nbN,256,0,stream>>>(rowptr, blksum, N, E);
  k_fill<<<nbE,256,0,stream>>>(srcArr, dstArr, dinv, rowptr, cur, colsrc, colnrm, E);
  k_copyx<<<(N*32 + 255)/256,256,0,stream>>>((const float4*)x, out, N*32);

  for (int l=0; l<3; l++){
    k_gemm<<<(N + 63)/64,256,0,stream>>>(out + l*128, Ws + (size_t)l*128*128, h, N);
    k_zero_f32<<<1,256,0,stream>>>(stats, 256);
    k_agg<<<(N + 31)/32,128,0,stream>>>(h, rowptr, colsrc, colnrm, dinv, out,
                                        (l+1)*128, stats, N);
    k_bnrelu<<<((N*128) + 255)/256,256,0,stream>>>(out, (l+1)*128, stats,
                                                   gammas + l*128, betas + l*128, N);
  }
}